// Round 12
// baseline (64.792 us; speedup 1.0000x reference)
//
#include <hip/hip_runtime.h>

// Problem constants
#define B_   8
#define L_   128
#define S_   160
#define H_   768
#define T_   16
#define CD_  50
#define WD_  100
#define NGATE 200   // 4*CD
#define NEGV (-1e30f)
#define FMAXV 3.402823466e+38f
#define NELEM (B_ * S_ * H_)      // 983040 floats in bert_emb

typedef short  s16x8 __attribute__((ext_vector_type(8)));   // 8 bf16 in 4 VGPRs
typedef float  f32x4 __attribute__((ext_vector_type(4)));

// ---- dynamic-LDS region offsets (bytes) for klstm ----
#define WBF_OFF    0
#define WBF_BYTES  (NGATE * 256)              // 200 rows x 128 bf16 (wi k0..63 | wh k0..63), swizzled
#define XALL_OFF   (WBF_OFF + WBF_BYTES)      // 51200
#define XALL_BYTES (T_ * 128 * 16)            // 32768
#define HBUF_OFF   (XALL_OFF + XALL_BYTES)    // 83968
#define HBUF_BYTES (2 * 128 * 16)             // 4096
#define META_OFF   (HBUF_OFF + HBUF_BYTES)    // 88064
#define SMEM_TOTAL (META_OFF + 32 * 4)        // 88192

__device__ __forceinline__ unsigned short f2bf(float f) {   // f32 -> bf16 RNE
    unsigned u = __float_as_uint(f);
    u = (u + 0x7FFFu + ((u >> 16) & 1u)) >> 16;
    return (unsigned short)u;
}
__device__ __forceinline__ float sigm(float x) {
    return __fdividef(1.f, 1.f + __expf(-x));
}
__device__ __forceinline__ float tanh_fast(float x) {
    float a = fabsf(x);
    float e = __expf(-2.f * a);
    float t = __fdividef(1.f - e, 1.f + e);
    return copysignf(t, x);
}
__device__ __forceinline__ float4 fmax4(float4 a, float4 b) {
    return make_float4(fmaxf(a.x, b.x), fmaxf(a.y, b.y), fmaxf(a.z, b.z), fmaxf(a.w, b.w));
}

// ================== Kernel 1: MFMA BiLSTM, LDS-resident bf16 weights ==================
// Weight N-order permuted: col j' = 4*cell + gate (orig row j = gate*50 + cell).
// B-fragments are ds_read_b128 from swizzled LDS EVERY STEP -> nothing for the register
// allocator to rematerialize from global (R6/R10/R11: VGPR<needed proved it did).
__global__ __launch_bounds__(256, 1) void klstm_mfma(
        const int* __restrict__ char_ids, const int* __restrict__ char_count,
        const int* __restrict__ tok_mask, const float* __restrict__ char_table,
        const float* __restrict__ w_ih_f, const float* __restrict__ w_hh_f,
        const float* __restrict__ b_f,
        const float* __restrict__ w_ih_b, const float* __restrict__ w_hh_b,
        const float* __restrict__ b_b,
        float* __restrict__ out) {
    extern __shared__ __align__(16) char smem[];
    unsigned short* wb16 = (unsigned short*)(smem + WBF_OFF);
    s16x8*          xal  = (s16x8*)(smem + XALL_OFF);
    s16x8*          hb   = (s16x8*)(smem + HBUF_OFF);
    int*            slen = (int*)(smem + META_OFF);
    int*            smask = slen + 16;

    const int unit = blockIdx.x;       // 0..127
    const int dir  = unit >> 6;
    const int grp  = unit & 63;        // 16 seqs
    const int tid  = threadIdx.x;
    const int lane = tid & 63;
    const int wv   = tid >> 6;

    const float* WI = dir ? w_ih_b : w_ih_f;
    const float* WH = dir ? w_hh_b : w_hh_f;
    const float* BV = dir ? b_b    : b_f;

    // ---- phase 1: metadata + zero hbuf + zero wbf (incl. k-pad columns) ----
    if (tid < 16) {
        int n = grp * 16 + tid;
        int c = char_count[n];
        slen[tid] = (c > 0) ? c : 1;
        int mb = 0;
        for (int t = 0; t < T_; ++t) mb |= (tok_mask[n * T_ + t] != 0) << t;
        smask[tid] = mb;
    }
    { s16x8 z = {0,0,0,0,0,0,0,0};
      if (tid < 256) { hb[tid] = z; }                       // 256 units = both buffers
      for (int i = tid; i < WBF_BYTES / 16; i += 256) ((s16x8*)wb16)[i] = z; }
    __syncthreads();   // wbf zero + slen visible

    // ---- phase 2a: stage weights coalesced -> swizzled bf16 LDS ----
    for (int idx = tid; idx < NGATE * CD_; idx += 256) {
        int j = idx / CD_, k = idx - j * CD_;
        int sw = (j & 7) << 4;
        wb16[(j * 256 + ((k * 2) ^ sw)) >> 1]        = f2bf(WI[idx]);
        wb16[(j * 256 + (((64 + k) * 2) ^ sw)) >> 1] = f2bf(WH[idx]);
    }

    // ---- phase 2b: prestage ALL x A-frags (reversed+zero-pad for bwd) ----
    for (int idx = tid; idx < T_ * 128; idx += 256) {
        int t = idx >> 7;
        int u = idx & 127;
        int g = u >> 4, s = u & 15;
        int st = dir ? (slen[s] - 1 - t) : t;
        s16x8 fr = {0,0,0,0,0,0,0,0};
        if (st >= 0) {
            int cidv = char_ids[(grp * 16 + s) * T_ + st];
            const float* row = char_table + cidv * CD_;
            int kbase = g * 8;
#pragma unroll
            for (int e = 0; e < 8; ++e) {
                int k = kbase + e;
                if (k < CD_) fr[e] = (short)f2bf(row[k]);
            }
        }
        xal[t * 128 + u] = fr;
    }

    // ---- phase 2c: per-lane geometry + B-frag LDS addresses + bias (registers only) ----
    const int m   = lane & 3;          // gate type
    const int k2  = (lane >> 2) & 3;   // cell sub-idx within tile
    const int q   = lane >> 4;
    const int sstar = q * 4 + m;       // seq owned after transpose
    const int cnt = (wv == 0) ? 4 : 3;

    int   ccol[4], cvld[4], hofs[4], ba[4][4];
    float bv[4];
#pragma unroll
    for (int i = 0; i < 4; ++i) {
        int nt = (i < 3) ? (wv + 4 * i) : 12;
        int c  = nt * 4 + k2;
        int jv = (i < cnt) && (c < CD_);
        ccol[i] = c;
        cvld[i] = jv;
        hofs[i] = ((c >> 3) * 16 + sstar) * 8 + (c & 7);
        int orow = m * 50 + c;
        bv[i] = jv ? BV[orow] : 0.f;
        int ora = (orow > NGATE - 1) ? (NGATE - 1) : orow;   // clamp addr; garbage cols land in cvld=0 lanes only
        int sw  = (ora & 7) << 4;
#pragma unroll
        for (int kt = 0; kt < 4; ++kt) {
            int col = kt * 32 + q * 8;
            ba[i][kt] = ora * 256 + ((col * 2) ^ sw);
        }
    }

    const int laneofs = (q << 4) + (lane & 15);   // kg*16 + s (A-frag read offset)
    const int sl_s = slen[sstar];
    const int sm_s = smask[sstar];

    float cst0 = 0.f, cst1 = 0.f, cst2 = 0.f, cst3 = 0.f;
    float mr0 = NEGV, mr1 = NEGV, mr2 = NEGV, mr3 = NEGV;
    const bool m0 = (lane & 1) != 0;
    const bool m1 = (lane & 2) != 0;

    __syncthreads();   // wbf values + xall + hbuf ready

    const char* wb = (const char*)wb16;
#define BFR(I, KT) (*(const s16x8*)(wb + ba[I][KT]))

    // 4x4 in-register transpose (2-stage shfl_xor) + LSTM cell update (verified R11)
#define TRUPD(I, D) { \
    float v0 = (D)[0], v1 = (D)[1], v2 = (D)[2], v3 = (D)[3]; \
    float s10 = __shfl_xor(v0, 1), s11 = __shfl_xor(v1, 1); \
    float s12 = __shfl_xor(v2, 1), s13 = __shfl_xor(v3, 1); \
    float A0 = m0 ? s11 : v0; \
    float A1 = m0 ? v1 : s10; \
    float A2 = m0 ? s13 : v2; \
    float A3 = m0 ? v3 : s12; \
    float s20 = __shfl_xor(A0, 2), s21 = __shfl_xor(A1, 2); \
    float s22 = __shfl_xor(A2, 2), s23 = __shfl_xor(A3, 2); \
    float gi = m1 ? s22 : A0; \
    float gf = m1 ? s23 : A1; \
    float gg = m1 ? A2 : s20; \
    float go = m1 ? A3 : s21; \
    float cc = sigm(gf) * cst##I + sigm(gi) * tanh_fast(gg); \
    float h  = sigm(go) * tanh_fast(cc); \
    if (cvld[I]) { \
        cst##I = cc; \
        hw[hofs[I]] = f2bf(h); \
        int tt = dir ? (sl_s - 1 - t) : t; \
        if (tt >= 0 && ((sm_s >> tt) & 1)) mr##I = fmaxf(mr##I, h); \
    } }

#pragma unroll 1
    for (int t = 0; t < T_; ++t) {
        const int cur = t & 1, nxt = cur ^ 1;
        unsigned short* hw = (unsigned short*)(smem + HBUF_OFF) + nxt * 1024;
        const s16x8* xb = xal + t * 128;
        s16x8 a0 = xb[laneofs];
        s16x8 a1 = xb[64 + laneofs];
        s16x8 a2 = hb[cur * 128 + laneofs];
        s16x8 a3 = hb[cur * 128 + 64 + laneofs];

        // tiles 0,1 (co-issued for MFMA/LDS overlap)
        {
            f32x4 d0 = {bv[0], bv[0], bv[0], bv[0]};
            f32x4 d1 = {bv[1], bv[1], bv[1], bv[1]};
            d0 = __builtin_amdgcn_mfma_f32_16x16x32_bf16(a0, BFR(0,0), d0, 0, 0, 0);
            d1 = __builtin_amdgcn_mfma_f32_16x16x32_bf16(a0, BFR(1,0), d1, 0, 0, 0);
            d0 = __builtin_amdgcn_mfma_f32_16x16x32_bf16(a1, BFR(0,1), d0, 0, 0, 0);
            d1 = __builtin_amdgcn_mfma_f32_16x16x32_bf16(a1, BFR(1,1), d1, 0, 0, 0);
            d0 = __builtin_amdgcn_mfma_f32_16x16x32_bf16(a2, BFR(0,2), d0, 0, 0, 0);
            d1 = __builtin_amdgcn_mfma_f32_16x16x32_bf16(a2, BFR(1,2), d1, 0, 0, 0);
            d0 = __builtin_amdgcn_mfma_f32_16x16x32_bf16(a3, BFR(0,3), d0, 0, 0, 0);
            d1 = __builtin_amdgcn_mfma_f32_16x16x32_bf16(a3, BFR(1,3), d1, 0, 0, 0);
            TRUPD(0, d0)
            TRUPD(1, d1)
        }
        // tile 2 (all waves), tile 3 (wave 0 only; wave-uniform branch)
        {
            f32x4 d2 = {bv[2], bv[2], bv[2], bv[2]};
            d2 = __builtin_amdgcn_mfma_f32_16x16x32_bf16(a0, BFR(2,0), d2, 0, 0, 0);
            d2 = __builtin_amdgcn_mfma_f32_16x16x32_bf16(a1, BFR(2,1), d2, 0, 0, 0);
            d2 = __builtin_amdgcn_mfma_f32_16x16x32_bf16(a2, BFR(2,2), d2, 0, 0, 0);
            d2 = __builtin_amdgcn_mfma_f32_16x16x32_bf16(a3, BFR(2,3), d2, 0, 0, 0);
            TRUPD(2, d2)
            if (cnt == 4) {
                f32x4 d3 = {bv[3], bv[3], bv[3], bv[3]};
                d3 = __builtin_amdgcn_mfma_f32_16x16x32_bf16(a0, BFR(3,0), d3, 0, 0, 0);
                d3 = __builtin_amdgcn_mfma_f32_16x16x32_bf16(a1, BFR(3,1), d3, 0, 0, 0);
                d3 = __builtin_amdgcn_mfma_f32_16x16x32_bf16(a2, BFR(3,2), d3, 0, 0, 0);
                d3 = __builtin_amdgcn_mfma_f32_16x16x32_bf16(a3, BFR(3,3), d3, 0, 0, 0);
                TRUPD(3, d3)
            }
        }
        __syncthreads();   // h(t) visible for step t+1
    }

    // ---- epilogue: pooled outputs ----
    float* ob = out + (size_t)(grp * 16 + sstar) * 968 + 868 + dir * CD_;
#define OUTW(I) if (cvld[I]) { \
    float mm = mr##I; \
    if (dir && (sm_s >> sl_s)) mm = fmaxf(mm, 0.f); \
    if (mm == NEGV) mm = 0.f; \
    ob[ccol[I]] = mm; }
    OUTW(0) OUTW(1) OUTW(2) OUTW(3)
}

// ================== Kernel 2: word_reps maxpool (float4, 8-deep) + word_embed + cls ==================
__global__ __launch_bounds__(256) void kword(const float* __restrict__ bert, const int* __restrict__ p2w,
                                             const int* __restrict__ word_ids, const float* __restrict__ word_table,
                                             float* __restrict__ out) {
    __shared__ int list[S_ + 8];
    __shared__ int cnt;
    __shared__ float red[256];
    int bl = blockIdx.x;          // b*128 + l
    int b = bl >> 7;
    int l = bl & 127;
    int tid = threadIdx.x;

    if (tid == 0) cnt = 0;
    __syncthreads();
    if (tid < S_) {
        if (p2w[bl * S_ + tid]) {
            int p = atomicAdd(&cnt, 1);   // order-independent: fmax is exact-commutative
            list[p] = tid;
        }
    }
    __syncthreads();
    int n = cnt;

    float* orow = out + (size_t)bl * 968;

    if (n > 0) {                          // n is block-uniform
        if (tid < ((8 - (n & 7)) & 7)) list[n + tid] = list[0];   // pad (idempotent)
        __syncthreads();
        int n8 = (n + 7) & ~7;
        if (tid < 192) {
            const float4* bb = (const float4*)(bert + (size_t)b * S_ * H_) + tid;
            float4 mx = make_float4(-FMAXV, -FMAXV, -FMAXV, -FMAXV);
            for (int i = 0; i < n8; i += 8) {
                float4 v0 = bb[(size_t)list[i]     * 192];
                float4 v1 = bb[(size_t)list[i + 1] * 192];
                float4 v2 = bb[(size_t)list[i + 2] * 192];
                float4 v3 = bb[(size_t)list[i + 3] * 192];
                float4 v4 = bb[(size_t)list[i + 4] * 192];
                float4 v5 = bb[(size_t)list[i + 5] * 192];
                float4 v6 = bb[(size_t)list[i + 6] * 192];
                float4 v7 = bb[(size_t)list[i + 7] * 192];
                mx = fmax4(mx, fmax4(fmax4(fmax4(v0, v1), fmax4(v2, v3)),
                                     fmax4(fmax4(v4, v5), fmax4(v6, v7))));
            }
            ((float4*)orow)[tid] = mx;
        } else {
            int j = tid - 192;
            int wid = word_ids[bl];
            orow[768 + j] = word_table[(size_t)wid * WD_ + j];
            if (j < WD_ - 64) orow[768 + 64 + j] = word_table[(size_t)wid * WD_ + 64 + j];
        }
    } else {
        // all-masked word (probability ~2^-160; kept for strict correctness)
        float mv = FMAXV;
        const float4* x4 = (const float4*)bert;
        for (int i = tid; i < NELEM / 4; i += 256) {
            float4 v = x4[i];
            mv = fminf(mv, fminf(fminf(v.x, v.y), fminf(v.z, v.w)));
        }
        red[tid] = mv;
        __syncthreads();
        for (int o = 128; o > 0; o >>= 1) {
            if (tid < o) red[tid] = fminf(red[tid], red[tid + o]);
            __syncthreads();
        }
        float g = red[0];
        if (tid < 192) {
            ((float4*)orow)[tid] = make_float4(g, g, g, g);
        } else {
            int j = tid - 192;
            int wid = word_ids[bl];
            orow[768 + j] = word_table[(size_t)wid * WD_ + j];
            if (j < WD_ - 64) orow[768 + 64 + j] = word_table[(size_t)wid * WD_ + 64 + j];
        }
    }

    if (l == 0 && tid < 192) {   // cls embedding = bert_emb[b,0,:]
        const float4* c4 = (const float4*)(bert + (size_t)b * S_ * H_);
        float4* co = (float4*)(out + (size_t)B_ * L_ * 968 + (size_t)b * H_);
        co[tid] = c4[tid];
    }
}

extern "C" void kernel_launch(void* const* d_in, const int* in_sizes, int n_in,
                              void* d_out, int out_size, void* d_ws, size_t ws_size,
                              hipStream_t stream) {
    const float* bert       = (const float*)d_in[0];
    const int*   p2w        = (const int*)d_in[1];
    const int*   word_ids   = (const int*)d_in[2];
    const int*   char_ids   = (const int*)d_in[3];
    const int*   char_count = (const int*)d_in[4];
    const int*   tok_mask   = (const int*)d_in[5];
    const float* word_table = (const float*)d_in[6];
    const float* char_table = (const float*)d_in[7];
    const float* w_ih_f = (const float*)d_in[8];
    const float* w_hh_f = (const float*)d_in[9];
    const float* b_f    = (const float*)d_in[10];
    const float* w_ih_b = (const float*)d_in[11];
    const float* w_hh_b = (const float*)d_in[12];
    const float* b_b    = (const float*)d_in[13];

    float* out = (float*)d_out;

    klstm_mfma<<<128, 256, SMEM_TOTAL, stream>>>(char_ids, char_count, tok_mask, char_table,
                                                 w_ih_f, w_hh_f, b_f, w_ih_b, w_hh_b, b_b, out);
    kword<<<B_ * L_, 256, 0, stream>>>(bert, p2w, word_ids, word_table, out);
}

// Round 13
// 45.145 us; speedup vs baseline: 1.4352x; 1.4352x over previous
//
#include <hip/hip_runtime.h>

// Problem constants
#define B_   8
#define L_   128
#define S_   160
#define H_   768
#define T_   16
#define CD_  50
#define WD_  100
#define NGATE 200   // 4*CD
#define NEGV (-1e30f)
#define FMAXV 3.402823466e+38f
#define NELEM (B_ * S_ * H_)      // 983040 floats in bert_emb

typedef short  s16x8 __attribute__((ext_vector_type(8)));   // 8 bf16 in 4 VGPRs
typedef float  f32x4 __attribute__((ext_vector_type(4)));

__device__ __forceinline__ unsigned short f2bf(float f) {   // f32 -> bf16 RNE
    unsigned u = __float_as_uint(f);
    u = (u + 0x7FFFu + ((u >> 16) & 1u)) >> 16;
    return (unsigned short)u;
}
__device__ __forceinline__ float sigm(float x) {
    return __fdividef(1.f, 1.f + __expf(-x));
}
__device__ __forceinline__ float tanh_fast(float x) {
    float a = fabsf(x);
    float e = __expf(-2.f * a);
    float t = __fdividef(1.f - e, 1.f + e);
    return copysignf(t, x);
}
__device__ __forceinline__ float4 fmax4(float4 a, float4 b) {
    return make_float4(fmaxf(a.x, b.x), fmaxf(a.y, b.y), fmaxf(a.z, b.z), fmaxf(a.w, b.w));
}

// ---------------- shared-memory overlays ----------------
struct LstmS {
    s16x8 xall[T_][128];   // x A-frags for every t              32768 B
    s16x8 hbuf[2][128];    // h A-frags, double-buffered          4096 B
    int   slen[16], smask[16];
};
struct WordS {
    int list[S_ + 8];
    int cnt;
    float red[256];
};
#define SMEM_BYTES 37120

// ================== role A: MFMA BiLSTM, gate-permuted weights, bias-in-K ==================
// Weight N-order permuted: col j' = 4*cell + gatetype (orig row j = gatetype*50 + cell).
// Bias folded into K: x[k=63] == 1.0, B[k=63][j'] = bias[j]  -> accumulators init from
// literal zero; the t-loop touches NO global memory and NO LDS metadata.
__device__ void lstm_body(int unit, char* smem,
        const int* __restrict__ char_ids, const int* __restrict__ char_count,
        const int* __restrict__ tok_mask, const float* __restrict__ char_table,
        const float* __restrict__ w_ih_f, const float* __restrict__ w_hh_f,
        const float* __restrict__ b_f,
        const float* __restrict__ w_ih_b, const float* __restrict__ w_hh_b,
        const float* __restrict__ b_b,
        float* __restrict__ out) {
    LstmS& sh = *(LstmS*)smem;
    const int dir  = unit >> 6;
    const int grp  = unit & 63;        // 16 seqs: grp*16 ..
    const int tid  = threadIdx.x;
    const int lane = tid & 63;
    const int wv   = tid >> 6;

    // ---- prologue: metadata + zero h buffers ----
    if (tid < 16) {
        int n = grp * 16 + tid;
        int c = char_count[n];
        sh.slen[tid] = (c > 0) ? c : 1;
        int mb = 0;
        for (int t = 0; t < T_; ++t) mb |= (tok_mask[n * T_ + t] != 0) << t;
        sh.smask[tid] = mb;
    }
    { s16x8 z = {0,0,0,0,0,0,0,0};
      if (tid < 128) sh.hbuf[0][tid] = z; else sh.hbuf[1][tid - 128] = z; }

    // ---- per-lane geometry ----
    const int m   = lane & 3;          // gate type (B cols) / seq sub-idx (after transpose)
    const int k2  = (lane >> 2) & 3;   // cell sub-idx within tile
    const int q   = lane >> 4;
    const int sstar = q * 4 + m;       // seq owned after transpose (same for all tiles)

    // ---- B-fragments (permuted weights + bias row at k=63) -> registers, once ----
    const float* WI = dir ? w_ih_b : w_ih_f;
    const float* WH = dir ? w_hh_b : w_hh_f;
    const float* BV = dir ? b_b    : b_f;
    const int cnt = (wv == 0) ? 4 : 3;
    int   ccol[4];      // cell index per tile
    int   cvld[4];      // col valid per tile
    int   hofs[4];      // h writeback ushort offset per tile
    s16x8 bf[4][4];
#pragma unroll
    for (int i = 0; i < 4; ++i) {
        int nt = (i < 3) ? (wv + 4 * i) : 12;
        int c  = nt * 4 + k2;
        int jv = (i < cnt) && (c < 50);
        ccol[i] = c;
        cvld[i] = jv;
        hofs[i] = ((c >> 3) * 16 + sstar) * 8 + (c & 7);
        int orow = m * 50 + c;                      // original weight row (gate m, cell c)
        const float* wi = WI + orow * CD_;
        const float* wh = WH + orow * CD_;
#pragma unroll
        for (int kt = 0; kt < 4; ++kt) {
            int kst = kt * 32 + q * 8;
            s16x8 fr = {0,0,0,0,0,0,0,0};
#pragma unroll
            for (int e = 0; e < 8; ++e) {
                int k = kst + e;
                float v = 0.f;
                if (jv) {
                    if (k < 64) {
                        if (k < CD_) v = wi[k];
                        else if (k == 63) v = BV[orow];   // bias-in-K column
                    } else {
                        int kk = k - 64;
                        if (kk < CD_) v = wh[kk];
                    }
                }
                fr[e] = (short)f2bf(v);
            }
            bf[i][kt] = fr;
        }
    }
    __syncthreads();   // slen ready

    // ---- prestage ALL x A-frags (16 t x 128 units); reversed+zero-pad for bwd ----
    // k=63 is ALWAYS 1.0 (bias multiplier) -- even on padded steps (reference applies
    // bias there too: x_rev row is zero but b is added).
    for (int idx = tid; idx < T_ * 128; idx += 256) {
        int t = idx >> 7;
        int u = idx & 127;
        int g = u >> 4, s = u & 15;
        int st = dir ? (sh.slen[s] - 1 - t) : t;
        s16x8 fr = {0,0,0,0,0,0,0,0};
        if (st >= 0) {
            int cidv = char_ids[(grp * 16 + s) * T_ + st];
            const float* row = char_table + cidv * CD_;
            int kbase = g * 8;
#pragma unroll
            for (int e = 0; e < 8; ++e) {
                int k = kbase + e;
                if (k < CD_) fr[e] = (short)f2bf(row[k]);
            }
        }
        if (g == 7) fr[7] = (short)0x3F80;     // bf16(1.0) at k=63
        sh.xall[t][u] = fr;
    }

    const int laneofs = (q << 4) + (lane & 15);   // kg*16 + s (A-frag read offset)
    const int sl_s = sh.slen[sstar];
    const int sm_s = sh.smask[sstar];

    // per-lane step mask in STEP order (bit t set => pool h of step t)
    int sms = 0;
#pragma unroll
    for (int t = 0; t < T_; ++t) {
        int tt = dir ? (sl_s - 1 - t) : t;
        if (tt >= 0 && ((sm_s >> tt) & 1)) sms |= 1 << t;
    }

    float cst0 = 0.f, cst1 = 0.f, cst2 = 0.f, cst3 = 0.f;
    float mr0 = NEGV, mr1 = NEGV, mr2 = NEGV, mr3 = NEGV;
    const bool m0 = (lane & 1) != 0;
    const bool m1 = (lane & 2) != 0;

    __syncthreads();   // xall + hbuf ready

    // 4x4 in-register transpose (2-stage shfl_xor) + LSTM cell update (verified R11)
#define TRUPD(I, D) { \
    float v0 = (D)[0], v1 = (D)[1], v2 = (D)[2], v3 = (D)[3]; \
    float s10 = __shfl_xor(v0, 1), s11 = __shfl_xor(v1, 1); \
    float s12 = __shfl_xor(v2, 1), s13 = __shfl_xor(v3, 1); \
    float A0 = m0 ? s11 : v0; \
    float A1 = m0 ? v1 : s10; \
    float A2 = m0 ? s13 : v2; \
    float A3 = m0 ? v3 : s12; \
    float s20 = __shfl_xor(A0, 2), s21 = __shfl_xor(A1, 2); \
    float s22 = __shfl_xor(A2, 2), s23 = __shfl_xor(A3, 2); \
    float gi = m1 ? s22 : A0; \
    float gf = m1 ? s23 : A1; \
    float gg = m1 ? A2 : s20; \
    float go = m1 ? A3 : s21; \
    float cc = sigm(gf) * cst##I + sigm(gi) * tanh_fast(gg); \
    float h  = sigm(go) * tanh_fast(cc); \
    if (cvld[I]) { \
        cst##I = cc; \
        hw[hofs[I]] = f2bf(h); \
        if ((sms >> t) & 1) mr##I = fmaxf(mr##I, h); \
    } }

    __builtin_amdgcn_s_setprio(1);   // LSTM waves are the serial pole; word waves yield

#pragma unroll 1
    for (int t = 0; t < T_; ++t) {
        const int cur = t & 1, nxt = cur ^ 1;
        unsigned short* hw = (unsigned short*)&sh.hbuf[nxt][0];
        const s16x8* xb = sh.xall[t];
        s16x8 a0 = xb[laneofs];
        s16x8 a1 = xb[64 + laneofs];
        s16x8 a2 = sh.hbuf[cur][laneofs];
        s16x8 a3 = sh.hbuf[cur][64 + laneofs];

        // tiles 0,1
        {
            f32x4 d0 = {0.f, 0.f, 0.f, 0.f};
            f32x4 d1 = {0.f, 0.f, 0.f, 0.f};
            d0 = __builtin_amdgcn_mfma_f32_16x16x32_bf16(a0, bf[0][0], d0, 0, 0, 0);
            d1 = __builtin_amdgcn_mfma_f32_16x16x32_bf16(a0, bf[1][0], d1, 0, 0, 0);
            d0 = __builtin_amdgcn_mfma_f32_16x16x32_bf16(a1, bf[0][1], d0, 0, 0, 0);
            d1 = __builtin_amdgcn_mfma_f32_16x16x32_bf16(a1, bf[1][1], d1, 0, 0, 0);
            d0 = __builtin_amdgcn_mfma_f32_16x16x32_bf16(a2, bf[0][2], d0, 0, 0, 0);
            d1 = __builtin_amdgcn_mfma_f32_16x16x32_bf16(a2, bf[1][2], d1, 0, 0, 0);
            d0 = __builtin_amdgcn_mfma_f32_16x16x32_bf16(a3, bf[0][3], d0, 0, 0, 0);
            d1 = __builtin_amdgcn_mfma_f32_16x16x32_bf16(a3, bf[1][3], d1, 0, 0, 0);
            TRUPD(0, d0)
            TRUPD(1, d1)
        }
        // tile 2 (all waves), tile 3 (wave 0 only; wave-uniform branch)
        {
            f32x4 d2 = {0.f, 0.f, 0.f, 0.f};
            d2 = __builtin_amdgcn_mfma_f32_16x16x32_bf16(a0, bf[2][0], d2, 0, 0, 0);
            d2 = __builtin_amdgcn_mfma_f32_16x16x32_bf16(a1, bf[2][1], d2, 0, 0, 0);
            d2 = __builtin_amdgcn_mfma_f32_16x16x32_bf16(a2, bf[2][2], d2, 0, 0, 0);
            d2 = __builtin_amdgcn_mfma_f32_16x16x32_bf16(a3, bf[2][3], d2, 0, 0, 0);
            TRUPD(2, d2)
            if (cnt == 4) {
                f32x4 d3 = {0.f, 0.f, 0.f, 0.f};
                d3 = __builtin_amdgcn_mfma_f32_16x16x32_bf16(a0, bf[3][0], d3, 0, 0, 0);
                d3 = __builtin_amdgcn_mfma_f32_16x16x32_bf16(a1, bf[3][1], d3, 0, 0, 0);
                d3 = __builtin_amdgcn_mfma_f32_16x16x32_bf16(a2, bf[3][2], d3, 0, 0, 0);
                d3 = __builtin_amdgcn_mfma_f32_16x16x32_bf16(a3, bf[3][3], d3, 0, 0, 0);
                TRUPD(3, d3)
            }
        }
        __syncthreads();   // h(t) visible for step t+1
    }

    __builtin_amdgcn_s_setprio(0);

    // ---- epilogue: pooled outputs (lane owns (cell,seq) pairs) ----
    float* ob = out + (size_t)(grp * 16 + sstar) * 968 + 868 + dir * CD_;
#define OUTW(I) if (cvld[I]) { \
    float mm = mr##I; \
    if (dir && (sm_s >> sl_s)) mm = fmaxf(mm, 0.f); \
    if (mm == NEGV) mm = 0.f; \
    ob[ccol[I]] = mm; }
    OUTW(0) OUTW(1) OUTW(2) OUTW(3)
}

// ================== role B: word_reps maxpool (float4, 8-deep) + word_embed + cls ==================
__device__ void word_body(int bl, char* smem,
        const float* __restrict__ bert, const int* __restrict__ p2w,
        const int* __restrict__ word_ids, const float* __restrict__ word_table,
        float* __restrict__ out) {
    WordS& sh = *(WordS*)smem;
    int b = bl >> 7;
    int l = bl & 127;
    int tid = threadIdx.x;

    if (tid == 0) sh.cnt = 0;
    __syncthreads();
    if (tid < S_) {
        if (p2w[bl * S_ + tid]) {
            int p = atomicAdd(&sh.cnt, 1);   // order-independent: fmax is exact-commutative
            sh.list[p] = tid;
        }
    }
    __syncthreads();
    int n = sh.cnt;

    float* orow = out + (size_t)bl * 968;

    if (n > 0) {                          // n is block-uniform
        if (tid < ((8 - (n & 7)) & 7)) sh.list[n + tid] = sh.list[0];   // pad (idempotent)
        __syncthreads();
        int n8 = (n + 7) & ~7;
        if (tid < 192) {
            const float4* bb = (const float4*)(bert + (size_t)b * S_ * H_) + tid;
            float4 mx = make_float4(-FMAXV, -FMAXV, -FMAXV, -FMAXV);
            for (int i = 0; i < n8; i += 8) {
                float4 v0 = bb[(size_t)sh.list[i]     * 192];
                float4 v1 = bb[(size_t)sh.list[i + 1] * 192];
                float4 v2 = bb[(size_t)sh.list[i + 2] * 192];
                float4 v3 = bb[(size_t)sh.list[i + 3] * 192];
                float4 v4 = bb[(size_t)sh.list[i + 4] * 192];
                float4 v5 = bb[(size_t)sh.list[i + 5] * 192];
                float4 v6 = bb[(size_t)sh.list[i + 6] * 192];
                float4 v7 = bb[(size_t)sh.list[i + 7] * 192];
                mx = fmax4(mx, fmax4(fmax4(fmax4(v0, v1), fmax4(v2, v3)),
                                     fmax4(fmax4(v4, v5), fmax4(v6, v7))));
            }
            ((float4*)orow)[tid] = mx;
        } else {
            int j = tid - 192;
            int wid = word_ids[bl];
            orow[768 + j] = word_table[(size_t)wid * WD_ + j];
            if (j < WD_ - 64) orow[768 + 64 + j] = word_table[(size_t)wid * WD_ + 64 + j];
        }
    } else {
        // all-masked word (probability ~2^-160; kept for strict correctness)
        float mv = FMAXV;
        const float4* x4 = (const float4*)bert;
        for (int i = tid; i < NELEM / 4; i += 256) {
            float4 v = x4[i];
            mv = fminf(mv, fminf(fminf(v.x, v.y), fminf(v.z, v.w)));
        }
        sh.red[tid] = mv;
        __syncthreads();
        for (int o = 128; o > 0; o >>= 1) {
            if (tid < o) sh.red[tid] = fminf(sh.red[tid], sh.red[tid + o]);
            __syncthreads();
        }
        float g = sh.red[0];
        if (tid < 192) {
            ((float4*)orow)[tid] = make_float4(g, g, g, g);
        } else {
            int j = tid - 192;
            int wid = word_ids[bl];
            orow[768 + j] = word_table[(size_t)wid * WD_ + j];
            if (j < WD_ - 64) orow[768 + 64 + j] = word_table[(size_t)wid * WD_ + 64 + j];
        }
    }

    if (l == 0 && tid < 192) {   // cls embedding = bert_emb[b,0,:]
        const float4* c4 = (const float4*)(bert + (size_t)b * S_ * H_);
        float4* co = (float4*)(out + (size_t)B_ * L_ * 968 + (size_t)b * H_);
        co[tid] = c4[tid];
    }
}

// ================== mega kernel: 128 LSTM blocks first, 1024 word blocks backfill ==================
__global__ __launch_bounds__(256, 1) void kmega(
        const float* __restrict__ bert, const int* __restrict__ p2w,
        const int* __restrict__ word_ids, const int* __restrict__ char_ids,
        const int* __restrict__ char_count, const int* __restrict__ tok_mask,
        const float* __restrict__ word_table, const float* __restrict__ char_table,
        const float* __restrict__ w_ih_f, const float* __restrict__ w_hh_f,
        const float* __restrict__ b_f,
        const float* __restrict__ w_ih_b, const float* __restrict__ w_hh_b,
        const float* __restrict__ b_b,
        float* __restrict__ out) {
    __shared__ __align__(16) char smem[SMEM_BYTES];
    int bid = blockIdx.x;
    if (bid < 128) {
        lstm_body(bid, smem, char_ids, char_count, tok_mask, char_table,
                  w_ih_f, w_hh_f, b_f, w_ih_b, w_hh_b, b_b, out);
    } else {
        word_body(bid - 128, smem, bert, p2w, word_ids, word_table, out);
    }
}

extern "C" void kernel_launch(void* const* d_in, const int* in_sizes, int n_in,
                              void* d_out, int out_size, void* d_ws, size_t ws_size,
                              hipStream_t stream) {
    const float* bert       = (const float*)d_in[0];
    const int*   p2w        = (const int*)d_in[1];
    const int*   word_ids   = (const int*)d_in[2];
    const int*   char_ids   = (const int*)d_in[3];
    const int*   char_count = (const int*)d_in[4];
    const int*   tok_mask   = (const int*)d_in[5];
    const float* word_table = (const float*)d_in[6];
    const float* char_table = (const float*)d_in[7];
    const float* w_ih_f = (const float*)d_in[8];
    const float* w_hh_f = (const float*)d_in[9];
    const float* b_f    = (const float*)d_in[10];
    const float* w_ih_b = (const float*)d_in[11];
    const float* w_hh_b = (const float*)d_in[12];
    const float* b_b    = (const float*)d_in[13];

    float* out = (float*)d_out;

    kmega<<<128 + B_ * L_, 256, 0, stream>>>(bert, p2w, word_ids, char_ids, char_count, tok_mask,
                                             word_table, char_table,
                                             w_ih_f, w_hh_f, b_f, w_ih_b, w_hh_b, b_b, out);
}

// Round 14
// 40.208 us; speedup vs baseline: 1.6114x; 1.1228x over previous
//
#include <hip/hip_runtime.h>

// Problem constants
#define B_   8
#define L_   128
#define S_   160
#define H_   768
#define T_   16
#define CD_  50
#define WD_  100
#define NGATE 200   // 4*CD
#define NEGV (-1e30f)
#define FMAXV 3.402823466e+38f
#define NELEM (B_ * S_ * H_)      // 983040 floats in bert_emb

typedef short  s16x8 __attribute__((ext_vector_type(8)));   // 8 bf16 in 4 VGPRs
typedef float  f32x4 __attribute__((ext_vector_type(4)));

__device__ __forceinline__ unsigned short f2bf(float f) {   // f32 -> bf16 RNE
    unsigned u = __float_as_uint(f);
    u = (u + 0x7FFFu + ((u >> 16) & 1u)) >> 16;
    return (unsigned short)u;
}
__device__ __forceinline__ float sigm(float x) {
    return __fdividef(1.f, 1.f + __expf(-x));
}
__device__ __forceinline__ float tanh_fast(float x) {
    float a = fabsf(x);
    float e = __expf(-2.f * a);
    float t = __fdividef(1.f - e, 1.f + e);
    return copysignf(t, x);
}
__device__ __forceinline__ float4 fmax4(float4 a, float4 b) {
    return make_float4(fmaxf(a.x, b.x), fmaxf(a.y, b.y), fmaxf(a.z, b.z), fmaxf(a.w, b.w));
}

// ---------------- shared-memory overlays ----------------
struct LstmS {
    s16x8 xall[T_][128];   // x A-frags for every t              32768 B
    s16x8 hbuf[2][128];    // h A-frags, double-buffered          4096 B
    int   slen[16], smask[16];
};
struct Word2S {            // two words per 512-thread block
    int   list[2][S_ + 8];
    int   cnt[2];
    float red[2][256];
};
#define SMEM_BYTES 37120

// ================== role A: MFMA BiLSTM, 8 waves x <=2 N-tiles ==================
// Weight N-order permuted: col j' = 4*cell + gatetype (orig row j = gatetype*50 + cell).
// Bias folded into K (x[k=63]=1, B[63][j']=bias). Per-wave B-footprint = 8 named s16x8
// (32 VGPR) so the allocator has no reason to remat/spill the weight fragments
// (R6..R13: VGPR 48..108 << needed proved the 16-frag version never stayed resident).
__device__ void lstm_body(int unit, char* smem,
        const int* __restrict__ char_ids, const int* __restrict__ char_count,
        const int* __restrict__ tok_mask, const float* __restrict__ char_table,
        const float* __restrict__ w_ih_f, const float* __restrict__ w_hh_f,
        const float* __restrict__ b_f,
        const float* __restrict__ w_ih_b, const float* __restrict__ w_hh_b,
        const float* __restrict__ b_b,
        float* __restrict__ out) {
    LstmS& sh = *(LstmS*)smem;
    const int dir  = unit >> 6;
    const int grp  = unit & 63;        // 16 seqs: grp*16 ..
    const int tid  = threadIdx.x;      // 0..511
    const int lane = tid & 63;
    const int wv   = tid >> 6;         // 0..7

    // ---- prologue: metadata + zero h buffers ----
    if (tid < 16) {
        int n = grp * 16 + tid;
        int c = char_count[n];
        sh.slen[tid] = (c > 0) ? c : 1;
        int mb = 0;
        for (int t = 0; t < T_; ++t) mb |= (tok_mask[n * T_ + t] != 0) << t;
        sh.smask[tid] = mb;
    }
    if (tid < 256) { s16x8 z = {0,0,0,0,0,0,0,0}; ((s16x8*)sh.hbuf)[tid] = z; }

    // ---- per-lane geometry ----
    const int m   = lane & 3;          // gate type (B cols) / seq sub-idx (after transpose)
    const int k2  = (lane >> 2) & 3;   // cell sub-idx within tile
    const int q   = lane >> 4;
    const int sstar = q * 4 + m;       // seq owned after transpose (same for all tiles)

    const float* WI = dir ? w_ih_b : w_ih_f;
    const float* WH = dir ? w_hh_b : w_hh_f;
    const float* BV = dir ? b_b    : b_f;

    // tiles: A = wv (0..7, always valid cols c<32<50), B = 8+wv (only wv<5)
    const int  ntA = wv;
    const int  ntB = 8 + wv;
    const bool hasB = (wv < 5);
    const int  cA = ntA * 4 + k2;                 // < 32, always valid
    const int  cB = ntB * 4 + k2;                 // 32..51
    const bool vB = hasB && (cB < CD_);
    const int  hofsA = ((cA >> 3) * 16 + sstar) * 8 + (cA & 7);
    const int  hofsB = ((cB >> 3) * 16 + sstar) * 8 + (cB & 7);

    // ---- B-fragments -> 8 NAMED registers (32 VGPR worst case) ----
#define LDFRAG(FR, OROW, KT, VALID) { \
    s16x8 fr_ = {0,0,0,0,0,0,0,0}; \
    if (VALID) { \
        const float* wi_ = WI + (OROW) * CD_; \
        const float* wh_ = WH + (OROW) * CD_; \
        int kst_ = (KT) * 32 + q * 8; \
        _Pragma("unroll") \
        for (int e = 0; e < 8; ++e) { \
            int k = kst_ + e; \
            float v = 0.f; \
            if (k < 64) { \
                if (k < CD_) v = wi_[k]; \
                else if (k == 63) v = BV[OROW]; \
            } else { \
                int kk = k - 64; \
                if (kk < CD_) v = wh_[kk]; \
            } \
            fr_[e] = (short)f2bf(v); \
        } \
    } \
    FR = fr_; }

    const int orowA = m * 50 + cA;
    const int orowB = m * 50 + ((cB < CD_) ? cB : 0);   // clamp; loads guarded by vB
    s16x8 bfA0, bfA1, bfA2, bfA3, bfB0, bfB1, bfB2, bfB3;
    LDFRAG(bfA0, orowA, 0, true)
    LDFRAG(bfA1, orowA, 1, true)
    LDFRAG(bfA2, orowA, 2, true)
    LDFRAG(bfA3, orowA, 3, true)
    LDFRAG(bfB0, orowB, 0, vB)
    LDFRAG(bfB1, orowB, 1, vB)
    LDFRAG(bfB2, orowB, 2, vB)
    LDFRAG(bfB3, orowB, 3, vB)
    __syncthreads();   // slen ready

    // ---- prestage ALL x A-frags (16 t x 128 units); k=63 always 1.0 (bias mult) ----
    for (int idx = tid; idx < T_ * 128; idx += 512) {
        int t = idx >> 7;
        int u = idx & 127;
        int g = u >> 4, s = u & 15;
        int st = dir ? (sh.slen[s] - 1 - t) : t;
        s16x8 fr = {0,0,0,0,0,0,0,0};
        if (st >= 0) {
            int cidv = char_ids[(grp * 16 + s) * T_ + st];
            const float* row = char_table + cidv * CD_;
            int kbase = g * 8;
#pragma unroll
            for (int e = 0; e < 8; ++e) {
                int k = kbase + e;
                if (k < CD_) fr[e] = (short)f2bf(row[k]);
            }
        }
        if (g == 7) fr[7] = (short)0x3F80;     // bf16(1.0) at k=63
        sh.xall[t][u] = fr;
    }

    const int laneofs = (q << 4) + (lane & 15);   // kg*16 + s (A-frag read offset)
    const int sl_s = sh.slen[sstar];
    const int sm_s = sh.smask[sstar];

    // per-lane step mask in STEP order (bit t set => pool h of step t)
    int sms = 0;
#pragma unroll
    for (int t = 0; t < T_; ++t) {
        int tt = dir ? (sl_s - 1 - t) : t;
        if (tt >= 0 && ((sm_s >> tt) & 1)) sms |= 1 << t;
    }

    float cstA = 0.f, cstB = 0.f;
    float mrA = NEGV, mrB = NEGV;
    const bool m0 = (lane & 1) != 0;
    const bool m1 = (lane & 2) != 0;

    __syncthreads();   // xall + hbuf ready

    // 4x4 in-register transpose (2-stage shfl_xor) + LSTM cell update (verified R11/R13)
#define TRUPD(VLD, HOF, CST, MR, D) { \
    float v0 = (D)[0], v1 = (D)[1], v2 = (D)[2], v3 = (D)[3]; \
    float s10 = __shfl_xor(v0, 1), s11 = __shfl_xor(v1, 1); \
    float s12 = __shfl_xor(v2, 1), s13 = __shfl_xor(v3, 1); \
    float A0 = m0 ? s11 : v0; \
    float A1 = m0 ? v1 : s10; \
    float A2 = m0 ? s13 : v2; \
    float A3 = m0 ? v3 : s12; \
    float s20 = __shfl_xor(A0, 2), s21 = __shfl_xor(A1, 2); \
    float s22 = __shfl_xor(A2, 2), s23 = __shfl_xor(A3, 2); \
    float gi = m1 ? s22 : A0; \
    float gf = m1 ? s23 : A1; \
    float gg = m1 ? A2 : s20; \
    float go = m1 ? A3 : s21; \
    float cc = sigm(gf) * (CST) + sigm(gi) * tanh_fast(gg); \
    float h  = sigm(go) * tanh_fast(cc); \
    if (VLD) { \
        CST = cc; \
        hw[HOF] = f2bf(h); \
        if ((sms >> t) & 1) MR = fmaxf(MR, h); \
    } }

    __builtin_amdgcn_s_setprio(1);   // LSTM waves are the serial pole

#pragma unroll 1
    for (int t = 0; t < T_; ++t) {
        const int cur = t & 1, nxt = cur ^ 1;
        unsigned short* hw = (unsigned short*)&sh.hbuf[nxt][0];
        const s16x8* xb = sh.xall[t];
        s16x8 a0 = xb[laneofs];
        s16x8 a1 = xb[64 + laneofs];
        s16x8 a2 = sh.hbuf[cur][laneofs];
        s16x8 a3 = sh.hbuf[cur][64 + laneofs];

        {
            f32x4 d0 = {0.f, 0.f, 0.f, 0.f};
            d0 = __builtin_amdgcn_mfma_f32_16x16x32_bf16(a0, bfA0, d0, 0, 0, 0);
            d0 = __builtin_amdgcn_mfma_f32_16x16x32_bf16(a1, bfA1, d0, 0, 0, 0);
            d0 = __builtin_amdgcn_mfma_f32_16x16x32_bf16(a2, bfA2, d0, 0, 0, 0);
            d0 = __builtin_amdgcn_mfma_f32_16x16x32_bf16(a3, bfA3, d0, 0, 0, 0);
            TRUPD(true, hofsA, cstA, mrA, d0)
        }
        if (hasB) {                       // wave-uniform branch; whole wave enters
            f32x4 d1 = {0.f, 0.f, 0.f, 0.f};
            d1 = __builtin_amdgcn_mfma_f32_16x16x32_bf16(a0, bfB0, d1, 0, 0, 0);
            d1 = __builtin_amdgcn_mfma_f32_16x16x32_bf16(a1, bfB1, d1, 0, 0, 0);
            d1 = __builtin_amdgcn_mfma_f32_16x16x32_bf16(a2, bfB2, d1, 0, 0, 0);
            d1 = __builtin_amdgcn_mfma_f32_16x16x32_bf16(a3, bfB3, d1, 0, 0, 0);
            TRUPD(vB, hofsB, cstB, mrB, d1)
        }
        __syncthreads();   // h(t) visible for step t+1
    }

    __builtin_amdgcn_s_setprio(0);

    // ---- epilogue: pooled outputs ----
    float* ob = out + (size_t)(grp * 16 + sstar) * 968 + 868 + dir * CD_;
    {
        float mm = mrA;
        if (dir && (sm_s >> sl_s)) mm = fmaxf(mm, 0.f);
        if (mm == NEGV) mm = 0.f;
        ob[cA] = mm;
    }
    if (vB) {
        float mm = mrB;
        if (dir && (sm_s >> sl_s)) mm = fmaxf(mm, 0.f);
        if (mm == NEGV) mm = 0.f;
        ob[cB] = mm;
    }
}

// ================== role B: two words per 512-thread block ==================
// Fixed 4-barrier schedule in BOTH paths (n>0 and the ~2^-160 n==0 fallback) so the
// two halves can never deadlock on mismatched __syncthreads counts.
__device__ void word_body2(int blk, char* smem,
        const float* __restrict__ bert, const int* __restrict__ p2w,
        const int* __restrict__ word_ids, const float* __restrict__ word_table,
        float* __restrict__ out) {
    Word2S& sh = *(Word2S*)smem;
    const int tid = threadIdx.x;       // 0..511
    const int h   = tid >> 8;          // which word half
    const int lid = tid & 255;
    const int bl  = blk * 2 + h;       // word index 0..1023
    const int b   = bl >> 7;
    const int l   = bl & 127;

    if (lid == 0) sh.cnt[h] = 0;
    __syncthreads();                                   // s1
    if (lid < S_) {
        if (p2w[bl * S_ + lid]) {
            int p = atomicAdd(&sh.cnt[h], 1);   // order-independent (fmax commutative)
            sh.list[h][p] = lid;
        }
    }
    __syncthreads();                                   // s2
    const int n = sh.cnt[h];
    if (n > 0 && lid < ((8 - (n & 7)) & 7)) sh.list[h][n + lid] = sh.list[h][0];
    __syncthreads();                                   // s3

    float gmin = 0.f;
    if (n == 0) {      // never in practice; kept for strict correctness
        float mv = FMAXV;
        const float4* x4 = (const float4*)bert;
        for (int i = lid; i < NELEM / 4; i += 256) {
            float4 v = x4[i];
            mv = fminf(mv, fminf(fminf(v.x, v.y), fminf(v.z, v.w)));
        }
        sh.red[h][lid] = mv;
    }
    __syncthreads();                                   // s4
    if (n == 0) {
        float g = FMAXV;
        for (int k = 0; k < 256; ++k) g = fminf(g, sh.red[h][k]);
        gmin = g;
    }

    float* orow = out + (size_t)bl * 968;
    if (n > 0) {
        int n8 = (n + 7) & ~7;
        if (lid < 192) {
            const float4* bb = (const float4*)(bert + (size_t)b * S_ * H_) + lid;
            float4 mx = make_float4(-FMAXV, -FMAXV, -FMAXV, -FMAXV);
            const int* lst = sh.list[h];
            for (int i = 0; i < n8; i += 8) {
                float4 v0 = bb[(size_t)lst[i]     * 192];
                float4 v1 = bb[(size_t)lst[i + 1] * 192];
                float4 v2 = bb[(size_t)lst[i + 2] * 192];
                float4 v3 = bb[(size_t)lst[i + 3] * 192];
                float4 v4 = bb[(size_t)lst[i + 4] * 192];
                float4 v5 = bb[(size_t)lst[i + 5] * 192];
                float4 v6 = bb[(size_t)lst[i + 6] * 192];
                float4 v7 = bb[(size_t)lst[i + 7] * 192];
                mx = fmax4(mx, fmax4(fmax4(fmax4(v0, v1), fmax4(v2, v3)),
                                     fmax4(fmax4(v4, v5), fmax4(v6, v7))));
            }
            ((float4*)orow)[lid] = mx;
        } else {
            int j = lid - 192;
            int wid = word_ids[bl];
            orow[768 + j] = word_table[(size_t)wid * WD_ + j];
            if (j < WD_ - 64) orow[768 + 64 + j] = word_table[(size_t)wid * WD_ + 64 + j];
        }
    } else {
        if (lid < 192) {
            ((float4*)orow)[lid] = make_float4(gmin, gmin, gmin, gmin);
        } else {
            int j = lid - 192;
            int wid = word_ids[bl];
            orow[768 + j] = word_table[(size_t)wid * WD_ + j];
            if (j < WD_ - 64) orow[768 + 64 + j] = word_table[(size_t)wid * WD_ + 64 + j];
        }
    }

    if (l == 0 && lid < 192) {   // cls embedding = bert_emb[b,0,:]
        const float4* c4 = (const float4*)(bert + (size_t)b * S_ * H_);
        float4* co = (float4*)(out + (size_t)B_ * L_ * 968 + (size_t)b * H_);
        co[lid] = c4[lid];
    }
}

// ================== mega kernel: 128 LSTM blocks first, 512 word blocks backfill ==================
__global__ __launch_bounds__(512, 2) void kmega(
        const float* __restrict__ bert, const int* __restrict__ p2w,
        const int* __restrict__ word_ids, const int* __restrict__ char_ids,
        const int* __restrict__ char_count, const int* __restrict__ tok_mask,
        const float* __restrict__ word_table, const float* __restrict__ char_table,
        const float* __restrict__ w_ih_f, const float* __restrict__ w_hh_f,
        const float* __restrict__ b_f,
        const float* __restrict__ w_ih_b, const float* __restrict__ w_hh_b,
        const float* __restrict__ b_b,
        float* __restrict__ out) {
    __shared__ __align__(16) char smem[SMEM_BYTES];
    int bid = blockIdx.x;
    if (bid < 128) {
        lstm_body(bid, smem, char_ids, char_count, tok_mask, char_table,
                  w_ih_f, w_hh_f, b_f, w_ih_b, w_hh_b, b_b, out);
    } else {
        word_body2(bid - 128, smem, bert, p2w, word_ids, word_table, out);
    }
}

extern "C" void kernel_launch(void* const* d_in, const int* in_sizes, int n_in,
                              void* d_out, int out_size, void* d_ws, size_t ws_size,
                              hipStream_t stream) {
    const float* bert       = (const float*)d_in[0];
    const int*   p2w        = (const int*)d_in[1];
    const int*   word_ids   = (const int*)d_in[2];
    const int*   char_ids   = (const int*)d_in[3];
    const int*   char_count = (const int*)d_in[4];
    const int*   tok_mask   = (const int*)d_in[5];
    const float* word_table = (const float*)d_in[6];
    const float* char_table = (const float*)d_in[7];
    const float* w_ih_f = (const float*)d_in[8];
    const float* w_hh_f = (const float*)d_in[9];
    const float* b_f    = (const float*)d_in[10];
    const float* w_ih_b = (const float*)d_in[11];
    const float* w_hh_b = (const float*)d_in[12];
    const float* b_b    = (const float*)d_in[13];

    float* out = (float*)d_out;

    kmega<<<128 + 512, 512, 0, stream>>>(bert, p2w, word_ids, char_ids, char_count, tok_mask,
                                         word_table, char_table,
                                         w_ih_f, w_hh_f, b_f, w_ih_b, w_hh_b, b_b, out);
}

// Round 15
// 39.602 us; speedup vs baseline: 1.6361x; 1.0153x over previous
//
#include <hip/hip_runtime.h>

// Problem constants
#define B_   8
#define L_   128
#define S_   160
#define H_   768
#define T_   16
#define CD_  50
#define WD_  100
#define NGATE 200   // 4*CD
#define NEGV (-1e30f)
#define FMAXV 3.402823466e+38f
#define NELEM (B_ * S_ * H_)      // 983040 floats in bert_emb

typedef short  s16x8 __attribute__((ext_vector_type(8)));   // 8 bf16 in 4 VGPRs
typedef float  f32x4 __attribute__((ext_vector_type(4)));

__device__ __forceinline__ unsigned short f2bf(float f) {   // f32 -> bf16 RNE
    unsigned u = __float_as_uint(f);
    u = (u + 0x7FFFu + ((u >> 16) & 1u)) >> 16;
    return (unsigned short)u;
}
__device__ __forceinline__ float sigm(float x) {
    return __fdividef(1.f, 1.f + __expf(-x));
}
__device__ __forceinline__ float tanh_fast(float x) {
    float a = fabsf(x);
    float e = __expf(-2.f * a);
    float t = __fdividef(1.f - e, 1.f + e);
    return copysignf(t, x);
}
__device__ __forceinline__ float4 fmax4(float4 a, float4 b) {
    return make_float4(fmaxf(a.x, b.x), fmaxf(a.y, b.y), fmaxf(a.z, b.z), fmaxf(a.w, b.w));
}

// ---------------- shared-memory overlays ----------------
struct LstmS {
    s16x8 xall[T_][128];   // x A-frags for every t              32768 B
    s16x8 hbuf[2][128];    // h A-frags, double-buffered          4096 B
    int   slen[16], smask[16];
};
struct Word2S {            // two words per 512-thread block
    int   list[2][S_ + 8];
    int   cnt[2];
    float red[2][256];
};
#define SMEM_BYTES 37120

// ================== role A: MFMA BiLSTM, 8 waves x <=2 N-tiles ==================
// Weight N-order permuted: col j' = 4*cell + gatetype (orig row j = gatetype*50 + cell).
// Bias folded into K (x[k=63]=1, B[63][j']=bias). Per-wave B-footprint = 8 named s16x8.
// waves_per_eu(2,4) on the kernel caps the scheduler's occupancy target at 4 waves/EU
// (VGPR budget 128) so the invariant-load remat stage stops re-gathering the weight
// fragments inside the t-loop (R6..R14: VGPR tracked the LDS-implied 64-reg budget).
__device__ void lstm_body(int unit, char* smem,
        const int* __restrict__ char_ids, const int* __restrict__ char_count,
        const int* __restrict__ tok_mask, const float* __restrict__ char_table,
        const float* __restrict__ w_ih_f, const float* __restrict__ w_hh_f,
        const float* __restrict__ b_f,
        const float* __restrict__ w_ih_b, const float* __restrict__ w_hh_b,
        const float* __restrict__ b_b,
        float* __restrict__ out) {
    LstmS& sh = *(LstmS*)smem;
    const int dir  = unit >> 6;
    const int grp  = unit & 63;        // 16 seqs: grp*16 ..
    const int tid  = threadIdx.x;      // 0..511
    const int lane = tid & 63;
    const int wv   = tid >> 6;         // 0..7

    // ---- prologue: metadata + zero h buffers ----
    if (tid < 16) {
        int n = grp * 16 + tid;
        int c = char_count[n];
        sh.slen[tid] = (c > 0) ? c : 1;
        int mb = 0;
        for (int t = 0; t < T_; ++t) mb |= (tok_mask[n * T_ + t] != 0) << t;
        sh.smask[tid] = mb;
    }
    if (tid < 256) { s16x8 z = {0,0,0,0,0,0,0,0}; ((s16x8*)sh.hbuf)[tid] = z; }

    // ---- per-lane geometry ----
    const int m   = lane & 3;          // gate type (B cols) / seq sub-idx (after transpose)
    const int k2  = (lane >> 2) & 3;   // cell sub-idx within tile
    const int q   = lane >> 4;
    const int sstar = q * 4 + m;       // seq owned after transpose (same for all tiles)

    const float* WI = dir ? w_ih_b : w_ih_f;
    const float* WH = dir ? w_hh_b : w_hh_f;
    const float* BV = dir ? b_b    : b_f;

    // tiles: A = wv (0..7, always valid cols c<32<50), B = 8+wv (only wv<5)
    const int  ntA = wv;
    const int  ntB = 8 + wv;
    const bool hasB = (wv < 5);
    const int  cA = ntA * 4 + k2;                 // < 32, always valid
    const int  cB = ntB * 4 + k2;                 // 32..51
    const bool vB = hasB && (cB < CD_);
    const int  hofsA = ((cA >> 3) * 16 + sstar) * 8 + (cA & 7);
    const int  hofsB = ((cB >> 3) * 16 + sstar) * 8 + (cB & 7);

    // ---- B-fragments -> 8 NAMED registers ----
#define LDFRAG(FR, OROW, KT, VALID) { \
    s16x8 fr_ = {0,0,0,0,0,0,0,0}; \
    if (VALID) { \
        const float* wi_ = WI + (OROW) * CD_; \
        const float* wh_ = WH + (OROW) * CD_; \
        int kst_ = (KT) * 32 + q * 8; \
        _Pragma("unroll") \
        for (int e = 0; e < 8; ++e) { \
            int k = kst_ + e; \
            float v = 0.f; \
            if (k < 64) { \
                if (k < CD_) v = wi_[k]; \
                else if (k == 63) v = BV[OROW]; \
            } else { \
                int kk = k - 64; \
                if (kk < CD_) v = wh_[kk]; \
            } \
            fr_[e] = (short)f2bf(v); \
        } \
    } \
    FR = fr_; }

    const int orowA = m * 50 + cA;
    const int orowB = m * 50 + ((cB < CD_) ? cB : 0);   // clamp; loads guarded by vB
    s16x8 bfA0, bfA1, bfA2, bfA3, bfB0, bfB1, bfB2, bfB3;
    LDFRAG(bfA0, orowA, 0, true)
    LDFRAG(bfA1, orowA, 1, true)
    LDFRAG(bfA2, orowA, 2, true)
    LDFRAG(bfA3, orowA, 3, true)
    LDFRAG(bfB0, orowB, 0, vB)
    LDFRAG(bfB1, orowB, 1, vB)
    LDFRAG(bfB2, orowB, 2, vB)
    LDFRAG(bfB3, orowB, 3, vB)
    __syncthreads();   // slen ready

    // ---- prestage ALL x A-frags (16 t x 128 units); k=63 always 1.0 (bias mult) ----
    for (int idx = tid; idx < T_ * 128; idx += 512) {
        int t = idx >> 7;
        int u = idx & 127;
        int g = u >> 4, s = u & 15;
        int st = dir ? (sh.slen[s] - 1 - t) : t;
        s16x8 fr = {0,0,0,0,0,0,0,0};
        if (st >= 0) {
            int cidv = char_ids[(grp * 16 + s) * T_ + st];
            const float* row = char_table + cidv * CD_;
            int kbase = g * 8;
#pragma unroll
            for (int e = 0; e < 8; ++e) {
                int k = kbase + e;
                if (k < CD_) fr[e] = (short)f2bf(row[k]);
            }
        }
        if (g == 7) fr[7] = (short)0x3F80;     // bf16(1.0) at k=63
        sh.xall[t][u] = fr;
    }

    const int laneofs = (q << 4) + (lane & 15);   // kg*16 + s (A-frag read offset)
    const int sl_s = sh.slen[sstar];
    const int sm_s = sh.smask[sstar];

    // per-lane step mask in STEP order (bit t set => pool h of step t)
    int sms = 0;
#pragma unroll
    for (int t = 0; t < T_; ++t) {
        int tt = dir ? (sl_s - 1 - t) : t;
        if (tt >= 0 && ((sm_s >> tt) & 1)) sms |= 1 << t;
    }

    float cstA = 0.f, cstB = 0.f;
    float mrA = NEGV, mrB = NEGV;
    const bool m0 = (lane & 1) != 0;
    const bool m1 = (lane & 2) != 0;

    __syncthreads();   // xall + hbuf ready

    // 4x4 in-register transpose (2-stage shfl_xor) + LSTM cell update (verified R11/R13)
#define TRUPD(VLD, HOF, CST, MR, D) { \
    float v0 = (D)[0], v1 = (D)[1], v2 = (D)[2], v3 = (D)[3]; \
    float s10 = __shfl_xor(v0, 1), s11 = __shfl_xor(v1, 1); \
    float s12 = __shfl_xor(v2, 1), s13 = __shfl_xor(v3, 1); \
    float A0 = m0 ? s11 : v0; \
    float A1 = m0 ? v1 : s10; \
    float A2 = m0 ? s13 : v2; \
    float A3 = m0 ? v3 : s12; \
    float s20 = __shfl_xor(A0, 2), s21 = __shfl_xor(A1, 2); \
    float s22 = __shfl_xor(A2, 2), s23 = __shfl_xor(A3, 2); \
    float gi = m1 ? s22 : A0; \
    float gf = m1 ? s23 : A1; \
    float gg = m1 ? A2 : s20; \
    float go = m1 ? A3 : s21; \
    float cc = sigm(gf) * (CST) + sigm(gi) * tanh_fast(gg); \
    float h  = sigm(go) * tanh_fast(cc); \
    if (VLD) { \
        CST = cc; \
        hw[HOF] = f2bf(h); \
        if ((sms >> t) & 1) MR = fmaxf(MR, h); \
    } }

    __builtin_amdgcn_s_setprio(1);   // LSTM waves are the serial pole

#pragma unroll 1
    for (int t = 0; t < T_; ++t) {
        const int cur = t & 1, nxt = cur ^ 1;
        unsigned short* hw = (unsigned short*)&sh.hbuf[nxt][0];
        const s16x8* xb = sh.xall[t];
        s16x8 a0 = xb[laneofs];
        s16x8 a1 = xb[64 + laneofs];
        s16x8 a2 = sh.hbuf[cur][laneofs];
        s16x8 a3 = sh.hbuf[cur][64 + laneofs];

        {
            f32x4 d0 = {0.f, 0.f, 0.f, 0.f};
            d0 = __builtin_amdgcn_mfma_f32_16x16x32_bf16(a0, bfA0, d0, 0, 0, 0);
            d0 = __builtin_amdgcn_mfma_f32_16x16x32_bf16(a1, bfA1, d0, 0, 0, 0);
            d0 = __builtin_amdgcn_mfma_f32_16x16x32_bf16(a2, bfA2, d0, 0, 0, 0);
            d0 = __builtin_amdgcn_mfma_f32_16x16x32_bf16(a3, bfA3, d0, 0, 0, 0);
            TRUPD(true, hofsA, cstA, mrA, d0)
        }
        if (hasB) {                       // wave-uniform branch; whole wave enters
            f32x4 d1 = {0.f, 0.f, 0.f, 0.f};
            d1 = __builtin_amdgcn_mfma_f32_16x16x32_bf16(a0, bfB0, d1, 0, 0, 0);
            d1 = __builtin_amdgcn_mfma_f32_16x16x32_bf16(a1, bfB1, d1, 0, 0, 0);
            d1 = __builtin_amdgcn_mfma_f32_16x16x32_bf16(a2, bfB2, d1, 0, 0, 0);
            d1 = __builtin_amdgcn_mfma_f32_16x16x32_bf16(a3, bfB3, d1, 0, 0, 0);
            TRUPD(vB, hofsB, cstB, mrB, d1)
        }
        __syncthreads();   // h(t) visible for step t+1
    }

    __builtin_amdgcn_s_setprio(0);

    // ---- epilogue: pooled outputs ----
    float* ob = out + (size_t)(grp * 16 + sstar) * 968 + 868 + dir * CD_;
    {
        float mm = mrA;
        if (dir && (sm_s >> sl_s)) mm = fmaxf(mm, 0.f);
        if (mm == NEGV) mm = 0.f;
        ob[cA] = mm;
    }
    if (vB) {
        float mm = mrB;
        if (dir && (sm_s >> sl_s)) mm = fmaxf(mm, 0.f);
        if (mm == NEGV) mm = 0.f;
        ob[cB] = mm;
    }
}

// ================== role B: two words per 512-thread block ==================
// Fixed 4-barrier schedule in BOTH paths so the two halves can never deadlock.
__device__ void word_body2(int blk, char* smem,
        const float* __restrict__ bert, const int* __restrict__ p2w,
        const int* __restrict__ word_ids, const float* __restrict__ word_table,
        float* __restrict__ out) {
    Word2S& sh = *(Word2S*)smem;
    const int tid = threadIdx.x;       // 0..511
    const int h   = tid >> 8;          // which word half
    const int lid = tid & 255;
    const int bl  = blk * 2 + h;       // word index 0..1023
    const int b   = bl >> 7;
    const int l   = bl & 127;

    if (lid == 0) sh.cnt[h] = 0;
    __syncthreads();                                   // s1
    if (lid < S_) {
        if (p2w[bl * S_ + lid]) {
            int p = atomicAdd(&sh.cnt[h], 1);   // order-independent (fmax commutative)
            sh.list[h][p] = lid;
        }
    }
    __syncthreads();                                   // s2
    const int n = sh.cnt[h];
    if (n > 0 && lid < ((8 - (n & 7)) & 7)) sh.list[h][n + lid] = sh.list[h][0];
    __syncthreads();                                   // s3

    float gmin = 0.f;
    if (n == 0) {      // never in practice; kept for strict correctness
        float mv = FMAXV;
        const float4* x4 = (const float4*)bert;
        for (int i = lid; i < NELEM / 4; i += 256) {
            float4 v = x4[i];
            mv = fminf(mv, fminf(fminf(v.x, v.y), fminf(v.z, v.w)));
        }
        sh.red[h][lid] = mv;
    }
    __syncthreads();                                   // s4
    if (n == 0) {
        float g = FMAXV;
        for (int k = 0; k < 256; ++k) g = fminf(g, sh.red[h][k]);
        gmin = g;
    }

    float* orow = out + (size_t)bl * 968;
    if (n > 0) {
        int n8 = (n + 7) & ~7;
        if (lid < 192) {
            const float4* bb = (const float4*)(bert + (size_t)b * S_ * H_) + lid;
            float4 mx = make_float4(-FMAXV, -FMAXV, -FMAXV, -FMAXV);
            const int* lst = sh.list[h];
            for (int i = 0; i < n8; i += 8) {
                float4 v0 = bb[(size_t)lst[i]     * 192];
                float4 v1 = bb[(size_t)lst[i + 1] * 192];
                float4 v2 = bb[(size_t)lst[i + 2] * 192];
                float4 v3 = bb[(size_t)lst[i + 3] * 192];
                float4 v4 = bb[(size_t)lst[i + 4] * 192];
                float4 v5 = bb[(size_t)lst[i + 5] * 192];
                float4 v6 = bb[(size_t)lst[i + 6] * 192];
                float4 v7 = bb[(size_t)lst[i + 7] * 192];
                mx = fmax4(mx, fmax4(fmax4(fmax4(v0, v1), fmax4(v2, v3)),
                                     fmax4(fmax4(v4, v5), fmax4(v6, v7))));
            }
            ((float4*)orow)[lid] = mx;
        } else {
            int j = lid - 192;
            int wid = word_ids[bl];
            orow[768 + j] = word_table[(size_t)wid * WD_ + j];
            if (j < WD_ - 64) orow[768 + 64 + j] = word_table[(size_t)wid * WD_ + 64 + j];
        }
    } else {
        if (lid < 192) {
            ((float4*)orow)[lid] = make_float4(gmin, gmin, gmin, gmin);
        } else {
            int j = lid - 192;
            int wid = word_ids[bl];
            orow[768 + j] = word_table[(size_t)wid * WD_ + j];
            if (j < WD_ - 64) orow[768 + 64 + j] = word_table[(size_t)wid * WD_ + 64 + j];
        }
    }

    if (l == 0 && lid < 192) {   // cls embedding = bert_emb[b,0,:]
        const float4* c4 = (const float4*)(bert + (size_t)b * S_ * H_);
        float4* co = (float4*)(out + (size_t)B_ * L_ * 968 + (size_t)b * H_);
        co[lid] = c4[lid];
    }
}

// ================== mega kernel: 128 LSTM blocks first, 512 word blocks backfill ==================
__global__ __launch_bounds__(512)
__attribute__((amdgpu_waves_per_eu(2, 4)))            // cap occupancy target: VGPR budget 128,
void kmega(                                           // stops invariant-load remat into t-loop
        const float* __restrict__ bert, const int* __restrict__ p2w,
        const int* __restrict__ word_ids, const int* __restrict__ char_ids,
        const int* __restrict__ char_count, const int* __restrict__ tok_mask,
        const float* __restrict__ word_table, const float* __restrict__ char_table,
        const float* __restrict__ w_ih_f, const float* __restrict__ w_hh_f,
        const float* __restrict__ b_f,
        const float* __restrict__ w_ih_b, const float* __restrict__ w_hh_b,
        const float* __restrict__ b_b,
        float* __restrict__ out) {
    __shared__ __align__(16) char smem[SMEM_BYTES];
    int bid = blockIdx.x;
    if (bid < 128) {
        lstm_body(bid, smem, char_ids, char_count, tok_mask, char_table,
                  w_ih_f, w_hh_f, b_f, w_ih_b, w_hh_b, b_b, out);
    } else {
        word_body2(bid - 128, smem, bert, p2w, word_ids, word_table, out);
    }
}

extern "C" void kernel_launch(void* const* d_in, const int* in_sizes, int n_in,
                              void* d_out, int out_size, void* d_ws, size_t ws_size,
                              hipStream_t stream) {
    const float* bert       = (const float*)d_in[0];
    const int*   p2w        = (const int*)d_in[1];
    const int*   word_ids   = (const int*)d_in[2];
    const int*   char_ids   = (const int*)d_in[3];
    const int*   char_count = (const int*)d_in[4];
    const int*   tok_mask   = (const int*)d_in[5];
    const float* word_table = (const float*)d_in[6];
    const float* char_table = (const float*)d_in[7];
    const float* w_ih_f = (const float*)d_in[8];
    const float* w_hh_f = (const float*)d_in[9];
    const float* b_f    = (const float*)d_in[10];
    const float* w_ih_b = (const float*)d_in[11];
    const float* w_hh_b = (const float*)d_in[12];
    const float* b_b    = (const float*)d_in[13];

    float* out = (float*)d_out;

    kmega<<<128 + 512, 512, 0, stream>>>(bert, p2w, word_ids, char_ids, char_count, tok_mask,
                                         word_table, char_table,
                                         w_ih_f, w_hh_f, b_f, w_ih_b, w_hh_b, b_b, out);
}